// Round 4
// baseline (1248.085 us; speedup 1.0000x reference)
//
#include <hip/hip_runtime.h>

#define B_ 8
#define N_ 8192
#define C_ 256
#define L_ 4
#define E_ 131072
#define BN_ 65536        // B_*N_
#define EDGES_ 1048576   // B_*E_

typedef __attribute__((ext_vector_type(8))) short short8;
typedef __attribute__((ext_vector_type(4))) float f32x4;

__device__ __forceinline__ unsigned short f2bf(float f){
  unsigned int u = __builtin_bit_cast(unsigned int, f);
  u += 0x7fffu + ((u >> 16) & 1u);
  return (unsigned short)(u >> 16);
}
__device__ __forceinline__ float bf2f(unsigned short h){
  unsigned int u = ((unsigned int)h) << 16;
  return __builtin_bit_cast(float, u);
}

// ---------------- f32 -> bf16 convert (x4 vectorized) ----------------
__launch_bounds__(256)
__global__ void cvt_bf16_k(const float* __restrict__ in, unsigned short* __restrict__ out, int n4){
  int t = blockIdx.x * 256 + threadIdx.x;
  if (t >= n4) return;
  float4 v = ((const float4*)in)[t];
  ushort4 o;
  o.x = f2bf(v.x); o.y = f2bf(v.y); o.z = f2bf(v.z); o.w = f2bf(v.w);
  ((ushort4*)out)[t] = o;
}

// ---------------- CSR build (counting sort by dst) ----------------
__launch_bounds__(256)
__global__ void hist_k(const int* __restrict__ ei, int* __restrict__ cnt){
  int t = blockIdx.x * 256 + threadIdx.x;
  int b = t >> 17, e = t & (E_ - 1);
  int dst = ei[b * (2 * E_) + E_ + e];
  atomicAdd(&cnt[(b << 13) + dst], 1);
}

__launch_bounds__(256)
__global__ void scan_k(const int* __restrict__ cnt, int* __restrict__ row_ptr, int* __restrict__ cursor){
  __shared__ int lsum[256];
  int t = threadIdx.x;
  int base = t << 8;
  int s = 0;
  for (int i = 0; i < 256; ++i) s += cnt[base + i];
  lsum[t] = s;
  __syncthreads();
  for (int d = 1; d < 256; d <<= 1){
    int v = (t >= d) ? lsum[t - d] : 0;
    __syncthreads();
    lsum[t] += v;
    __syncthreads();
  }
  int off = lsum[t] - s;   // exclusive prefix of this 256-chunk
  for (int i = 0; i < 256; ++i){
    row_ptr[base + i] = off;
    cursor[base + i]  = off;
    off += cnt[base + i];
  }
  if (t == 255) row_ptr[BN_] = off;
}

__launch_bounds__(256)
__global__ void scat_k(const int* __restrict__ ei, int* __restrict__ cursor, int* __restrict__ col){
  int t = blockIdx.x * 256 + threadIdx.x;
  int b = t >> 17, e = t & (E_ - 1);
  int src = ei[b * (2 * E_) + e];
  int dst = ei[b * (2 * E_) + E_ + e];
  int pos = atomicAdd(&cursor[(b << 13) + dst], 1);
  col[pos] = (b << 13) + src;
}

// ---- aggregation: one wave per dst node, CSR, bf16 gather, f32 accum ----
// blockIdx%8 = graph id -> pins each graph's 4 MiB bf16 table to one XCD's L2.
__launch_bounds__(256)
__global__ void agg_k(const unsigned short* __restrict__ feat, const int* __restrict__ row_ptr,
                      const int* __restrict__ col, unsigned short* __restrict__ out){
  int w = threadIdx.x >> 6, lane = threadIdx.x & 63;
  int g = blockIdx.x & 7, sblk = blockIdx.x >> 3;
  int node = (g << 13) + (sblk << 2) + w;
  int beg = row_ptr[node], end = row_ptr[node + 1];
  int ch = lane << 2;  // 4 channels per lane
  float a0=0,a1=0,a2=0,a3=0,b0=0,b1=0,b2=0,b3=0;
  int e = beg;
  for (; e + 2 <= end; e += 2){
    int s0 = col[e], s1 = col[e + 1];
    ushort4 v0 = *(const ushort4*)(feat + ((size_t)s0 << 8) + ch);
    ushort4 v1 = *(const ushort4*)(feat + ((size_t)s1 << 8) + ch);
    a0 += bf2f(v0.x); a1 += bf2f(v0.y); a2 += bf2f(v0.z); a3 += bf2f(v0.w);
    b0 += bf2f(v1.x); b1 += bf2f(v1.y); b2 += bf2f(v1.z); b3 += bf2f(v1.w);
  }
  if (e < end){
    int s0 = col[e];
    ushort4 v0 = *(const ushort4*)(feat + ((size_t)s0 << 8) + ch);
    a0 += bf2f(v0.x); a1 += bf2f(v0.y); a2 += bf2f(v0.z); a3 += bf2f(v0.w);
  }
  ushort4 o;
  o.x = f2bf(a0 + b0); o.y = f2bf(a1 + b1); o.z = f2bf(a2 + b2); o.w = f2bf(a3 + b3);
  *(ushort4*)(out + ((size_t)node << 8) + ch) = o;
}

// ---- fused dual aggregation: same CSR walk, gather two tables at once ----
__launch_bounds__(256)
__global__ void agg2_k(const unsigned short* __restrict__ fA, const unsigned short* __restrict__ fB,
                       const int* __restrict__ row_ptr, const int* __restrict__ col,
                       unsigned short* __restrict__ oA, unsigned short* __restrict__ oB){
  int w = threadIdx.x >> 6, lane = threadIdx.x & 63;
  int g = blockIdx.x & 7, sblk = blockIdx.x >> 3;
  int node = (g << 13) + (sblk << 2) + w;
  int beg = row_ptr[node], end = row_ptr[node + 1];
  int ch = lane << 2;
  float a0=0,a1=0,a2=0,a3=0, c0=0,c1=0,c2=0,c3=0;
  float a4=0,a5=0,a6=0,a7=0, c4=0,c5=0,c6=0,c7=0;
  int e = beg;
  for (; e + 2 <= end; e += 2){
    int s0 = col[e], s1 = col[e + 1];
    ushort4 va0 = *(const ushort4*)(fA + ((size_t)s0 << 8) + ch);
    ushort4 vb0 = *(const ushort4*)(fB + ((size_t)s0 << 8) + ch);
    ushort4 va1 = *(const ushort4*)(fA + ((size_t)s1 << 8) + ch);
    ushort4 vb1 = *(const ushort4*)(fB + ((size_t)s1 << 8) + ch);
    a0 += bf2f(va0.x); a1 += bf2f(va0.y); a2 += bf2f(va0.z); a3 += bf2f(va0.w);
    c0 += bf2f(vb0.x); c1 += bf2f(vb0.y); c2 += bf2f(vb0.z); c3 += bf2f(vb0.w);
    a4 += bf2f(va1.x); a5 += bf2f(va1.y); a6 += bf2f(va1.z); a7 += bf2f(va1.w);
    c4 += bf2f(vb1.x); c5 += bf2f(vb1.y); c6 += bf2f(vb1.z); c7 += bf2f(vb1.w);
  }
  if (e < end){
    int s0 = col[e];
    ushort4 va0 = *(const ushort4*)(fA + ((size_t)s0 << 8) + ch);
    ushort4 vb0 = *(const ushort4*)(fB + ((size_t)s0 << 8) + ch);
    a0 += bf2f(va0.x); a1 += bf2f(va0.y); a2 += bf2f(va0.z); a3 += bf2f(va0.w);
    c0 += bf2f(vb0.x); c1 += bf2f(vb0.y); c2 += bf2f(vb0.z); c3 += bf2f(vb0.w);
  }
  ushort4 oa, ob;
  oa.x = f2bf(a0 + a4); oa.y = f2bf(a1 + a5); oa.z = f2bf(a2 + a6); oa.w = f2bf(a3 + a7);
  ob.x = f2bf(c0 + c4); ob.y = f2bf(c1 + c5); ob.z = f2bf(c2 + c6); ob.w = f2bf(c3 + c7);
  *(ushort4*)(oA + ((size_t)node << 8) + ch) = oa;
  *(ushort4*)(oB + ((size_t)node << 8) + ch) = ob;
}

// ---------------- multi-operand GEMM: out = relu(sum_p A_p @ W_p.T + b) ----------------
// A_p: [65536, 256] bf16 row-major. W_p: [256, K] rows at stride ldw (B^T layout).
// 128x256 tile (full N per block -> A staged ONCE), 4 waves, wave tile 32x256,
// acc[2][16] (128 VGPRs), B-fragments consumed in two halves of 8 to cap VGPR.
#define GLDS16(gp, lp) __builtin_amdgcn_global_load_lds( \
    (const __attribute__((address_space(1))) void*)(gp), \
    (__attribute__((address_space(3))) void*)(lp), 16, 0, 0)

template<int P>
__launch_bounds__(256)
__global__ void gemm_k(const unsigned short* __restrict__ A0, const unsigned short* __restrict__ A1,
                       const unsigned short* __restrict__ A2, const unsigned short* __restrict__ A3,
                       const unsigned short* __restrict__ W0, const unsigned short* __restrict__ W1,
                       const unsigned short* __restrict__ W2, const unsigned short* __restrict__ W3,
                       int ldw, const float* __restrict__ bias,
                       unsigned short* __restrict__ outb, float* __restrict__ outf){
  __shared__ unsigned short lds_u[12288];           // 24 KiB: A-tile 8K + B-tile 16K
  unsigned short* a_t = lds_u;                       // [128][32]
  unsigned short* b_t = lds_u + 4096;                // [256][32]
  const unsigned short* As[4] = {A0, A1, A2, A3};
  const unsigned short* Ws[4] = {W0, W1, W2, W3};
  const int m0 = blockIdx.x << 7;
  const int t = threadIdx.x, lane = t & 63;
  const int w = t >> 6;                              // wave id: rows w*32..w*32+31
  const int lrow = lane & 15, kg = lane >> 4;
  f32x4 acc[2][16] = {};
#pragma unroll
  for (int p = 0; p < P; ++p){
    const unsigned short* A = As[p] + (size_t)m0 * C_;
    const unsigned short* W = Ws[p];
    for (int k0 = 0; k0 < C_; k0 += 32){
      // stage A-tile 128x32 (512 x 16B chunks) + B-tile 256x32 (1024 chunks)
#pragma unroll
      for (int c = t; c < 512; c += 256){
        int row = c >> 2, seg = c & 3;
        GLDS16(A + row * C_  + k0 + seg * 8, &a_t[c * 8]);
      }
#pragma unroll
      for (int c = t; c < 1024; c += 256){
        int row = c >> 2, seg = c & 3;
        GLDS16(W + row * ldw + k0 + seg * 8, &b_t[c * 8]);
      }
      __syncthreads();
      short8 af[2];
#pragma unroll
      for (int m = 0; m < 2; ++m)
        af[m] = *(const short8*)&a_t[((w << 5) + (m << 4) + lrow) * 32 + (kg << 3)];
#pragma unroll
      for (int h = 0; h < 2; ++h){                   // column halves: W rows h*128..h*128+127
        short8 bfr[8];
#pragma unroll
        for (int n2 = 0; n2 < 8; ++n2)
          bfr[n2] = *(const short8*)&b_t[((h << 7) + (n2 << 4) + lrow) * 32 + (kg << 3)];
#pragma unroll
        for (int m = 0; m < 2; ++m)
#pragma unroll
          for (int n2 = 0; n2 < 8; ++n2)
            acc[m][(h << 3) + n2] =
                __builtin_amdgcn_mfma_f32_16x16x32_bf16(af[m], bfr[n2], acc[m][(h << 3) + n2], 0, 0, 0);
      }
      __syncthreads();
    }
  }
  // ---- epilogue: bias + relu; f32 direct stores, bf16 via LDS transpose ----
  float bv[16];
#pragma unroll
  for (int n = 0; n < 16; ++n) bv[n] = bias[(n << 4) + lrow];
  unsigned short* ep = lds_u + (w << 11);            // 4 KiB private per wave [16][128]
#pragma unroll
  for (int m = 0; m < 2; ++m){
    const int gr = m0 + (w << 5) + (m << 4);
    if (outf){
#pragma unroll
      for (int n = 0; n < 16; ++n)
#pragma unroll
        for (int j = 0; j < 4; ++j){
          float v = acc[m][n][j] + bv[n];
          v = v > 0.f ? v : 0.f;
          outf[(size_t)(gr + (kg << 2) + j) * C_ + (n << 4) + lrow] = v;
        }
    }
    if (outb){
#pragma unroll
      for (int h = 0; h < 2; ++h){                   // column halves of 256
#pragma unroll
        for (int n2 = 0; n2 < 8; ++n2){
          int n = (h << 3) + n2;
#pragma unroll
          for (int j = 0; j < 4; ++j){
            float v = acc[m][n][j] + bv[n];
            v = v > 0.f ? v : 0.f;
            ep[((kg << 2) + j) * 128 + (n2 << 4) + lrow] = f2bf(v);
          }
        }
        // read back row-major, store coalesced 16B/lane (256B per row-instr)
#pragma unroll
        for (int k = 0; k < 4; ++k){
          int r = (lane >> 4) + (k << 2);
          short8 v = *(const short8*)&ep[r * 128 + (lane & 15) * 8];
          *(short8*)&outb[(size_t)(gr + r) * C_ + (h << 7) + (lane & 15) * 8] = v;
        }
      }
    }
  }
}

// ---------------------------------------------------------------------------
extern "C" void kernel_launch(void* const* d_in, const int* in_sizes, int n_in,
                              void* d_out, int out_size, void* d_ws, size_t ws_size,
                              hipStream_t stream){
  const float* x_f   = (const float*)d_in[0];
  const float* bWr_f = (const float*)d_in[1];
  const float* bWn_f = (const float*)d_in[2];
  const float* bB    = (const float*)d_in[3];
  const float* aWr_f = (const float*)d_in[4];
  const float* aWn_f = (const float*)d_in[5];
  const float* aB    = (const float*)d_in[6];
  const int*   ei    = (const int*)d_in[7];
  float* out = (float*)d_out;
  (void)in_sizes; (void)n_in; (void)out_size; (void)ws_size;

  char* p = (char*)d_ws;
  const size_t BUF = (size_t)BN_ * C_ * sizeof(unsigned short); // 32 MiB
  auto alloc = [&](size_t bytes){ void* r = (void*)p; p += (bytes + 255) & ~(size_t)255; return r; };
  unsigned short* xb   = (unsigned short*)alloc(BUF);
  unsigned short* latA = (unsigned short*)alloc(BUF);
  unsigned short* latB = (unsigned short*)alloc(BUF);
  unsigned short* curA = (unsigned short*)alloc(BUF);
  unsigned short* curB = (unsigned short*)alloc(BUF);
  unsigned short* agg0 = (unsigned short*)alloc(BUF);
  unsigned short* agg1 = (unsigned short*)alloc(BUF);
  unsigned short* wbR  = (unsigned short*)alloc((size_t)L_ * C_ * C_ * 2);
  unsigned short* wbN  = (unsigned short*)alloc((size_t)L_ * C_ * C_ * 2);
  unsigned short* waR  = (unsigned short*)alloc((size_t)L_ * C_ * 2 * C_ * 2);
  unsigned short* waN  = (unsigned short*)alloc((size_t)L_ * C_ * 2 * C_ * 2);
  int* cnt     = (int*)alloc((size_t)BN_ * 4);
  int* row_ptr = (int*)alloc((size_t)(BN_ + 1) * 4);
  int* cursor  = (int*)alloc((size_t)BN_ * 4);
  int* colx    = (int*)alloc((size_t)EDGES_ * 4);

  // bf16 conversions
  cvt_bf16_k<<<BN_ * C_ / 4 / 256, 256, 0, stream>>>(x_f, xb, BN_ * C_ / 4);
  cvt_bf16_k<<<L_ * C_ * C_ / 4 / 256, 256, 0, stream>>>(bWr_f, wbR, L_ * C_ * C_ / 4);
  cvt_bf16_k<<<L_ * C_ * C_ / 4 / 256, 256, 0, stream>>>(bWn_f, wbN, L_ * C_ * C_ / 4);
  cvt_bf16_k<<<L_ * C_ * 2 * C_ / 4 / 256, 256, 0, stream>>>(aWr_f, waR, L_ * C_ * 2 * C_ / 4);
  cvt_bf16_k<<<L_ * C_ * 2 * C_ / 4 / 256, 256, 0, stream>>>(aWn_f, waN, L_ * C_ * 2 * C_ / 4);

  // CSR build
  hipMemsetAsync(cnt, 0, (size_t)BN_ * 4, stream);
  hist_k<<<EDGES_ / 256, 256, 0, stream>>>(ei, cnt);
  scan_k<<<1, 256, 0, stream>>>(cnt, row_ptr, cursor);
  scat_k<<<EDGES_ / 256, 256, 0, stream>>>(ei, cursor, colx);

  const int AGG_GRID  = BN_ / 4;     // 16384 blocks, 4 waves/block, 1 node/wave
  const int GEMM_GRID = BN_ / 128;   // 512 blocks, full N per block

  const size_t WB = (size_t)C_ * C_;       // base per-layer weight elems
  const size_t WA = (size_t)C_ * 2 * C_;   // adapter per-layer weight elems

  // base layer 0: lat1 = relu(x@Wr0.T + agg(x)@Wn0.T + b0)
  agg_k<<<AGG_GRID, 256, 0, stream>>>(xb, row_ptr, colx, agg0);                 // agg(x)
  gemm_k<2><<<GEMM_GRID, 256, 0, stream>>>(xb, agg0, nullptr, nullptr,
      wbR, wbN, nullptr, nullptr, C_, bB, latA, nullptr);                        // lat1
  agg_k<<<AGG_GRID, 256, 0, stream>>>(latA, row_ptr, colx, agg1);               // agg(lat1)
  // base layer 1
  gemm_k<2><<<GEMM_GRID, 256, 0, stream>>>(latA, agg1, nullptr, nullptr,
      wbR + WB, wbN + WB, nullptr, nullptr, C_, bB + 256, latB, nullptr);        // lat2
  // adapter layer 0: concat(lat1, x)
  gemm_k<4><<<GEMM_GRID, 256, 0, stream>>>(latA, xb, agg1, agg0,
      waR, waR + 256, waN, waN + 256, 2 * C_, aB, curA, nullptr);                // curr1
  agg2_k<<<AGG_GRID, 256, 0, stream>>>(latB, curA, row_ptr, colx, agg1, agg0);  // agg(lat2), agg(curr1)
  // base layer 2
  gemm_k<2><<<GEMM_GRID, 256, 0, stream>>>(latB, agg1, nullptr, nullptr,
      wbR + 2 * WB, wbN + 2 * WB, nullptr, nullptr, C_, bB + 512, latA, nullptr); // lat3
  // adapter layer 1: concat(lat2, curr1)
  gemm_k<4><<<GEMM_GRID, 256, 0, stream>>>(latB, curA, agg1, agg0,
      waR + WA, waR + WA + 256, waN + WA, waN + WA + 256, 2 * C_, aB + 256, curB, nullptr); // curr2
  agg2_k<<<AGG_GRID, 256, 0, stream>>>(latA, curB, row_ptr, colx, agg1, agg0);  // agg(lat3), agg(curr2)
  // base layer 3 -> d_out first half (f32) + bf16 copy for agg(lat4)
  gemm_k<2><<<GEMM_GRID, 256, 0, stream>>>(latA, agg1, nullptr, nullptr,
      wbR + 3 * WB, wbN + 3 * WB, nullptr, nullptr, C_, bB + 768, latB, out);    // lat4
  // adapter layer 2: concat(lat3, curr2)
  gemm_k<4><<<GEMM_GRID, 256, 0, stream>>>(latA, curB, agg1, agg0,
      waR + 2 * WA, waR + 2 * WA + 256, waN + 2 * WA, waN + 2 * WA + 256, 2 * C_, aB + 512, curA, nullptr); // curr3
  agg2_k<<<AGG_GRID, 256, 0, stream>>>(latB, curA, row_ptr, colx, agg1, agg0);  // agg(lat4), agg(curr3)
  // adapter layer 3 -> d_out second half (f32 only)
  gemm_k<4><<<GEMM_GRID, 256, 0, stream>>>(latB, curA, agg1, agg0,
      waR + 3 * WA, waR + 3 * WA + 256, waN + 3 * WA, waN + 3 * WA + 256, 2 * C_, aB + 768,
      nullptr, out + (size_t)BN_ * C_);
}

// Round 5
// 1233.686 us; speedup vs baseline: 1.0117x; 1.0117x over previous
//
#include <hip/hip_runtime.h>

#define B_ 8
#define N_ 8192
#define C_ 256
#define L_ 4
#define E_ 131072
#define BN_ 65536        // B_*N_
#define EDGES_ 1048576   // B_*E_
#define NKEY_ (BN_ * 4)  // CSR keys: (node, src_tile of 2048)

typedef __attribute__((ext_vector_type(8))) short short8;
typedef __attribute__((ext_vector_type(4))) float f32x4;

__device__ __forceinline__ unsigned short f2bf(float f){
  unsigned int u = __builtin_bit_cast(unsigned int, f);
  u += 0x7fffu + ((u >> 16) & 1u);
  return (unsigned short)(u >> 16);
}
__device__ __forceinline__ float bf2f(unsigned short h){
  unsigned int u = ((unsigned int)h) << 16;
  return __builtin_bit_cast(float, u);
}

// ---------------- f32 -> bf16 convert (x4 vectorized) ----------------
__launch_bounds__(256)
__global__ void cvt_bf16_k(const float* __restrict__ in, unsigned short* __restrict__ out, int n4){
  int t = blockIdx.x * 256 + threadIdx.x;
  if (t >= n4) return;
  float4 v = ((const float4*)in)[t];
  ushort4 o;
  o.x = f2bf(v.x); o.y = f2bf(v.y); o.z = f2bf(v.z); o.w = f2bf(v.w);
  ((ushort4*)out)[t] = o;
}

// -------- CSR build: counting sort by key = (dst, src>>11) --------
// src-tile ordering makes concurrent gather waves touch a 1 MiB window per
// table (L2-resident per XCD) instead of cycling the whole 4 MiB table.
__launch_bounds__(256)
__global__ void hist_k(const int* __restrict__ ei, int* __restrict__ cnt){
  int t = blockIdx.x * 256 + threadIdx.x;
  int b = t >> 17, e = t & (E_ - 1);
  int src = ei[b * (2 * E_) + e];
  int dst = ei[b * (2 * E_) + E_ + e];
  int key = (((b << 13) + dst) << 2) | (src >> 11);
  atomicAdd(&cnt[key], 1);
}

__launch_bounds__(256)
__global__ void scan_k(const int* __restrict__ cnt, int* __restrict__ row_ptr, int* __restrict__ cursor){
  __shared__ int lsum[256];
  int t = threadIdx.x;
  const int CH = NKEY_ / 256;          // 1024 keys per thread
  int base = t * CH;
  int s = 0;
  const int4* c4 = (const int4*)(cnt + base);
  for (int i = 0; i < CH / 4; ++i){ int4 v = c4[i]; s += v.x + v.y + v.z + v.w; }
  lsum[t] = s;
  __syncthreads();
  for (int d = 1; d < 256; d <<= 1){
    int v = (t >= d) ? lsum[t - d] : 0;
    __syncthreads();
    lsum[t] += v;
    __syncthreads();
  }
  int off = lsum[t] - s;               // exclusive prefix of this chunk
  for (int i = 0; i < CH; ++i){
    row_ptr[base + i] = off;
    cursor[base + i]  = off;
    off += cnt[base + i];
  }
  if (t == 255) row_ptr[NKEY_] = off;
}

__launch_bounds__(256)
__global__ void scat_k(const int* __restrict__ ei, int* __restrict__ cursor, int* __restrict__ col){
  int t = blockIdx.x * 256 + threadIdx.x;
  int b = t >> 17, e = t & (E_ - 1);
  int src = ei[b * (2 * E_) + e];
  int dst = ei[b * (2 * E_) + E_ + e];
  int key = (((b << 13) + dst) << 2) | (src >> 11);
  int pos = atomicAdd(&cursor[key], 1);
  col[pos] = (b << 13) + src;
}

// ---- aggregation: one wave per dst node, CSR (src-tile ordered), f32 accum ----
// blockIdx%8 = graph id -> pins each graph's tables to one XCD's L2.
__launch_bounds__(256)
__global__ void agg_k(const unsigned short* __restrict__ feat, const int* __restrict__ row_ptr,
                      const int* __restrict__ col, unsigned short* __restrict__ out){
  int w = threadIdx.x >> 6, lane = threadIdx.x & 63;
  int g = blockIdx.x & 7, sblk = blockIdx.x >> 3;
  int node = (g << 13) + (sblk << 2) + w;
  int beg = row_ptr[node << 2], end = row_ptr[(node << 2) + 4];
  int ch = lane << 2;  // 4 channels per lane
  float a0=0,a1=0,a2=0,a3=0;
  int e = beg;
  for (; e + 4 <= end; e += 4){
    int s0 = col[e], s1 = col[e+1], s2 = col[e+2], s3 = col[e+3];
    ushort4 v0 = *(const ushort4*)(feat + ((size_t)s0 << 8) + ch);
    ushort4 v1 = *(const ushort4*)(feat + ((size_t)s1 << 8) + ch);
    ushort4 v2 = *(const ushort4*)(feat + ((size_t)s2 << 8) + ch);
    ushort4 v3 = *(const ushort4*)(feat + ((size_t)s3 << 8) + ch);
    a0 += (bf2f(v0.x) + bf2f(v1.x)) + (bf2f(v2.x) + bf2f(v3.x));
    a1 += (bf2f(v0.y) + bf2f(v1.y)) + (bf2f(v2.y) + bf2f(v3.y));
    a2 += (bf2f(v0.z) + bf2f(v1.z)) + (bf2f(v2.z) + bf2f(v3.z));
    a3 += (bf2f(v0.w) + bf2f(v1.w)) + (bf2f(v2.w) + bf2f(v3.w));
  }
  for (; e < end; ++e){
    int s0 = col[e];
    ushort4 v0 = *(const ushort4*)(feat + ((size_t)s0 << 8) + ch);
    a0 += bf2f(v0.x); a1 += bf2f(v0.y); a2 += bf2f(v0.z); a3 += bf2f(v0.w);
  }
  ushort4 o;
  o.x = f2bf(a0); o.y = f2bf(a1); o.z = f2bf(a2); o.w = f2bf(a3);
  *(ushort4*)(out + ((size_t)node << 8) + ch) = o;
}

// ---- fused dual aggregation: same CSR walk, gather two tables at once ----
__launch_bounds__(256)
__global__ void agg2_k(const unsigned short* __restrict__ fA, const unsigned short* __restrict__ fB,
                       const int* __restrict__ row_ptr, const int* __restrict__ col,
                       unsigned short* __restrict__ oA, unsigned short* __restrict__ oB){
  int w = threadIdx.x >> 6, lane = threadIdx.x & 63;
  int g = blockIdx.x & 7, sblk = blockIdx.x >> 3;
  int node = (g << 13) + (sblk << 2) + w;
  int beg = row_ptr[node << 2], end = row_ptr[(node << 2) + 4];
  int ch = lane << 2;
  float a0=0,a1=0,a2=0,a3=0, c0=0,c1=0,c2=0,c3=0;
  int e = beg;
  for (; e + 4 <= end; e += 4){
    int s0 = col[e], s1 = col[e+1], s2 = col[e+2], s3 = col[e+3];
    ushort4 va0 = *(const ushort4*)(fA + ((size_t)s0 << 8) + ch);
    ushort4 va1 = *(const ushort4*)(fA + ((size_t)s1 << 8) + ch);
    ushort4 va2 = *(const ushort4*)(fA + ((size_t)s2 << 8) + ch);
    ushort4 va3 = *(const ushort4*)(fA + ((size_t)s3 << 8) + ch);
    ushort4 vb0 = *(const ushort4*)(fB + ((size_t)s0 << 8) + ch);
    ushort4 vb1 = *(const ushort4*)(fB + ((size_t)s1 << 8) + ch);
    ushort4 vb2 = *(const ushort4*)(fB + ((size_t)s2 << 8) + ch);
    ushort4 vb3 = *(const ushort4*)(fB + ((size_t)s3 << 8) + ch);
    a0 += (bf2f(va0.x) + bf2f(va1.x)) + (bf2f(va2.x) + bf2f(va3.x));
    a1 += (bf2f(va0.y) + bf2f(va1.y)) + (bf2f(va2.y) + bf2f(va3.y));
    a2 += (bf2f(va0.z) + bf2f(va1.z)) + (bf2f(va2.z) + bf2f(va3.z));
    a3 += (bf2f(va0.w) + bf2f(va1.w)) + (bf2f(va2.w) + bf2f(va3.w));
    c0 += (bf2f(vb0.x) + bf2f(vb1.x)) + (bf2f(vb2.x) + bf2f(vb3.x));
    c1 += (bf2f(vb0.y) + bf2f(vb1.y)) + (bf2f(vb2.y) + bf2f(vb3.y));
    c2 += (bf2f(vb0.z) + bf2f(vb1.z)) + (bf2f(vb2.z) + bf2f(vb3.z));
    c3 += (bf2f(vb0.w) + bf2f(vb1.w)) + (bf2f(vb2.w) + bf2f(vb3.w));
  }
  for (; e < end; ++e){
    int s0 = col[e];
    ushort4 va0 = *(const ushort4*)(fA + ((size_t)s0 << 8) + ch);
    ushort4 vb0 = *(const ushort4*)(fB + ((size_t)s0 << 8) + ch);
    a0 += bf2f(va0.x); a1 += bf2f(va0.y); a2 += bf2f(va0.z); a3 += bf2f(va0.w);
    c0 += bf2f(vb0.x); c1 += bf2f(vb0.y); c2 += bf2f(vb0.z); c3 += bf2f(vb0.w);
  }
  ushort4 oa, ob;
  oa.x = f2bf(a0); oa.y = f2bf(a1); oa.z = f2bf(a2); oa.w = f2bf(a3);
  ob.x = f2bf(c0); ob.y = f2bf(c1); ob.z = f2bf(c2); ob.w = f2bf(c3);
  *(ushort4*)(oA + ((size_t)node << 8) + ch) = oa;
  *(ushort4*)(oB + ((size_t)node << 8) + ch) = ob;
}

// ---------------- multi-operand GEMM: out = relu(sum_p A_p @ W_p.T + b) ----------------
// 128x256 tile, 4 waves (wave tile 32x256, acc[2][16]).
// 2-phase pipeline (T3 minimum): double-buffered 24KB LDS, STAGE(next) issued
// before compute(cur), ONE vmcnt(0)+s_barrier per k-step (loads in flight
// during MFMA instead of full-drain __syncthreads x2).
#define GLDS16(gp, lp) __builtin_amdgcn_global_load_lds( \
    (const __attribute__((address_space(1))) void*)(gp), \
    (__attribute__((address_space(3))) void*)(lp), 16, 0, 0)

template<int P>
__launch_bounds__(256)
__global__ void gemm_k(const unsigned short* __restrict__ A0, const unsigned short* __restrict__ A1,
                       const unsigned short* __restrict__ A2, const unsigned short* __restrict__ A3,
                       const unsigned short* __restrict__ W0, const unsigned short* __restrict__ W1,
                       const unsigned short* __restrict__ W2, const unsigned short* __restrict__ W3,
                       int ldw, const float* __restrict__ bias,
                       unsigned short* __restrict__ outb, float* __restrict__ outf){
  __shared__ unsigned short lds_u[24576];            // 48 KiB: 2 x (A 8K + B 16K)
  const unsigned short* As[4] = {A0, A1, A2, A3};
  const unsigned short* Ws[4] = {W0, W1, W2, W3};
  const int m0 = blockIdx.x << 7;
  const int t = threadIdx.x, lane = t & 63;
  const int w = t >> 6;                              // wave id: rows w*32..w*32+31
  const int lrow = lane & 15, kg = lane >> 4;
  f32x4 acc[2][16] = {};
  int cur = 0;

#pragma unroll
  for (int p = 0; p < P; ++p){
    const unsigned short* A = As[p] + (size_t)m0 * C_;
    const unsigned short* W = Ws[p];
    // op prologue: stage k-step 0 into buf[cur], full drain
    {
      unsigned short* a_t = lds_u + cur * 12288;
      unsigned short* b_t = a_t + 4096;
#pragma unroll
      for (int c = t; c < 512; c += 256){
        int row = c >> 2, seg = c & 3;
        GLDS16(A + row * C_  + seg * 8, &a_t[c * 8]);
      }
#pragma unroll
      for (int c = t; c < 1024; c += 256){
        int row = c >> 2, seg = c & 3;
        GLDS16(W + row * ldw + seg * 8, &b_t[c * 8]);
      }
      asm volatile("s_waitcnt vmcnt(0)" ::: "memory");
      __builtin_amdgcn_s_barrier();
    }
    for (int ks = 0; ks < 8; ++ks){
      if (ks < 7){                                   // stage NEXT k-step into buf[cur^1]
        int k0 = (ks + 1) << 5;
        unsigned short* a_t = lds_u + (cur ^ 1) * 12288;
        unsigned short* b_t = a_t + 4096;
#pragma unroll
        for (int c = t; c < 512; c += 256){
          int row = c >> 2, seg = c & 3;
          GLDS16(A + row * C_  + k0 + seg * 8, &a_t[c * 8]);
        }
#pragma unroll
        for (int c = t; c < 1024; c += 256){
          int row = c >> 2, seg = c & 3;
          GLDS16(W + row * ldw + k0 + seg * 8, &b_t[c * 8]);
        }
      }
      // compute on buf[cur]
      {
        const unsigned short* a_t = lds_u + cur * 12288;
        const unsigned short* b_t = a_t + 4096;
        short8 af[2];
#pragma unroll
        for (int m = 0; m < 2; ++m)
          af[m] = *(const short8*)&a_t[((w << 5) + (m << 4) + lrow) * 32 + (kg << 3)];
#pragma unroll
        for (int h = 0; h < 2; ++h){
          short8 bfr[8];
#pragma unroll
          for (int n2 = 0; n2 < 8; ++n2)
            bfr[n2] = *(const short8*)&b_t[((h << 7) + (n2 << 4) + lrow) * 32 + (kg << 3)];
#pragma unroll
          for (int m = 0; m < 2; ++m)
#pragma unroll
            for (int n2 = 0; n2 < 8; ++n2)
              acc[m][(h << 3) + n2] =
                  __builtin_amdgcn_mfma_f32_16x16x32_bf16(af[m], bfr[n2], acc[m][(h << 3) + n2], 0, 0, 0);
        }
      }
      // next-tile loads complete + all waves done reading buf[cur]
      asm volatile("s_waitcnt vmcnt(0)" ::: "memory");
      __builtin_amdgcn_s_barrier();
      cur ^= 1;
    }
  }
  // ---- epilogue: bias + relu; both outputs via LDS transpose, coalesced ----
  // bf16 region: [0, 16K) bytes, 4KB/wave. f32 region: [16K, 48K), 8KB/wave.
  float bv[16];
#pragma unroll
  for (int n = 0; n < 16; ++n) bv[n] = bias[(n << 4) + lrow];
  unsigned short* ep  = lds_u + (w << 11);           // [16][128] bf16, 4KB
  float*          epf = (float*)(&lds_u[8192]) + (w << 11); // [16][128] f32, 8KB
#pragma unroll
  for (int m = 0; m < 2; ++m){
    const int gr = m0 + (w << 5) + (m << 4);
    if (outf){
#pragma unroll
      for (int h = 0; h < 2; ++h){
#pragma unroll
        for (int n2 = 0; n2 < 8; ++n2){
          int n = (h << 3) + n2;
#pragma unroll
          for (int j = 0; j < 4; ++j){
            float v = acc[m][n][j] + bv[n];
            v = v > 0.f ? v : 0.f;
            epf[((kg << 2) + j) * 128 + (n2 << 4) + lrow] = v;
          }
        }
#pragma unroll
        for (int k = 0; k < 8; ++k){
          int r = (lane >> 5) + (k << 1);
          float4 v = *(const float4*)&epf[r * 128 + (lane & 31) * 4];
          *(float4*)&outf[(size_t)(gr + r) * C_ + (h << 7) + (lane & 31) * 4] = v;
        }
      }
    }
    if (outb){
#pragma unroll
      for (int h = 0; h < 2; ++h){                   // column halves of 256
#pragma unroll
        for (int n2 = 0; n2 < 8; ++n2){
          int n = (h << 3) + n2;
#pragma unroll
          for (int j = 0; j < 4; ++j){
            float v = acc[m][n][j] + bv[n];
            v = v > 0.f ? v : 0.f;
            ep[((kg << 2) + j) * 128 + (n2 << 4) + lrow] = f2bf(v);
          }
        }
#pragma unroll
        for (int k = 0; k < 4; ++k){
          int r = (lane >> 4) + (k << 2);
          short8 v = *(const short8*)&ep[r * 128 + (lane & 15) * 8];
          *(short8*)&outb[(size_t)(gr + r) * C_ + (h << 7) + (lane & 15) * 8] = v;
        }
      }
    }
  }
}

// ---------------------------------------------------------------------------
extern "C" void kernel_launch(void* const* d_in, const int* in_sizes, int n_in,
                              void* d_out, int out_size, void* d_ws, size_t ws_size,
                              hipStream_t stream){
  const float* x_f   = (const float*)d_in[0];
  const float* bWr_f = (const float*)d_in[1];
  const float* bWn_f = (const float*)d_in[2];
  const float* bB    = (const float*)d_in[3];
  const float* aWr_f = (const float*)d_in[4];
  const float* aWn_f = (const float*)d_in[5];
  const float* aB    = (const float*)d_in[6];
  const int*   ei    = (const int*)d_in[7];
  float* out = (float*)d_out;
  (void)in_sizes; (void)n_in; (void)out_size; (void)ws_size;

  char* p = (char*)d_ws;
  const size_t BUF = (size_t)BN_ * C_ * sizeof(unsigned short); // 32 MiB
  auto alloc = [&](size_t bytes){ void* r = (void*)p; p += (bytes + 255) & ~(size_t)255; return r; };
  unsigned short* xb   = (unsigned short*)alloc(BUF);
  unsigned short* latA = (unsigned short*)alloc(BUF);
  unsigned short* latB = (unsigned short*)alloc(BUF);
  unsigned short* curA = (unsigned short*)alloc(BUF);
  unsigned short* curB = (unsigned short*)alloc(BUF);
  unsigned short* agg0 = (unsigned short*)alloc(BUF);
  unsigned short* agg1 = (unsigned short*)alloc(BUF);
  unsigned short* wbR  = (unsigned short*)alloc((size_t)L_ * C_ * C_ * 2);
  unsigned short* wbN  = (unsigned short*)alloc((size_t)L_ * C_ * C_ * 2);
  unsigned short* waR  = (unsigned short*)alloc((size_t)L_ * C_ * 2 * C_ * 2);
  unsigned short* waN  = (unsigned short*)alloc((size_t)L_ * C_ * 2 * C_ * 2);
  int* cnt     = (int*)alloc((size_t)NKEY_ * 4);
  int* row_ptr = (int*)alloc((size_t)(NKEY_ + 1) * 4);
  int* cursor  = (int*)alloc((size_t)NKEY_ * 4);
  int* colx    = (int*)alloc((size_t)EDGES_ * 4);

  // bf16 conversions
  cvt_bf16_k<<<BN_ * C_ / 4 / 256, 256, 0, stream>>>(x_f, xb, BN_ * C_ / 4);
  cvt_bf16_k<<<L_ * C_ * C_ / 4 / 256, 256, 0, stream>>>(bWr_f, wbR, L_ * C_ * C_ / 4);
  cvt_bf16_k<<<L_ * C_ * C_ / 4 / 256, 256, 0, stream>>>(bWn_f, wbN, L_ * C_ * C_ / 4);
  cvt_bf16_k<<<L_ * C_ * 2 * C_ / 4 / 256, 256, 0, stream>>>(aWr_f, waR, L_ * C_ * 2 * C_ / 4);
  cvt_bf16_k<<<L_ * C_ * 2 * C_ / 4 / 256, 256, 0, stream>>>(aWn_f, waN, L_ * C_ * 2 * C_ / 4);

  // CSR build (src-tiled counting sort)
  hipMemsetAsync(cnt, 0, (size_t)NKEY_ * 4, stream);
  hist_k<<<EDGES_ / 256, 256, 0, stream>>>(ei, cnt);
  scan_k<<<1, 256, 0, stream>>>(cnt, row_ptr, cursor);
  scat_k<<<EDGES_ / 256, 256, 0, stream>>>(ei, cursor, colx);

  const int AGG_GRID  = BN_ / 4;     // 16384 blocks, 4 waves/block, 1 node/wave
  const int GEMM_GRID = BN_ / 128;   // 512 blocks, full N per block

  const size_t WB = (size_t)C_ * C_;       // base per-layer weight elems
  const size_t WA = (size_t)C_ * 2 * C_;   // adapter per-layer weight elems

  // base layer 0: lat1 = relu(x@Wr0.T + agg(x)@Wn0.T + b0)
  agg_k<<<AGG_GRID, 256, 0, stream>>>(xb, row_ptr, colx, agg0);                 // agg(x)
  gemm_k<2><<<GEMM_GRID, 256, 0, stream>>>(xb, agg0, nullptr, nullptr,
      wbR, wbN, nullptr, nullptr, C_, bB, latA, nullptr);                        // lat1
  agg_k<<<AGG_GRID, 256, 0, stream>>>(latA, row_ptr, colx, agg1);               // agg(lat1)
  // base layer 1
  gemm_k<2><<<GEMM_GRID, 256, 0, stream>>>(latA, agg1, nullptr, nullptr,
      wbR + WB, wbN + WB, nullptr, nullptr, C_, bB + 256, latB, nullptr);        // lat2
  // adapter layer 0: concat(lat1, x)
  gemm_k<4><<<GEMM_GRID, 256, 0, stream>>>(latA, xb, agg1, agg0,
      waR, waR + 256, waN, waN + 256, 2 * C_, aB, curA, nullptr);                // curr1
  agg2_k<<<AGG_GRID, 256, 0, stream>>>(latB, curA, row_ptr, colx, agg1, agg0);  // agg(lat2), agg(curr1)
  // base layer 2
  gemm_k<2><<<GEMM_GRID, 256, 0, stream>>>(latB, agg1, nullptr, nullptr,
      wbR + 2 * WB, wbN + 2 * WB, nullptr, nullptr, C_, bB + 512, latA, nullptr); // lat3
  // adapter layer 1: concat(lat2, curr1)
  gemm_k<4><<<GEMM_GRID, 256, 0, stream>>>(latB, curA, agg1, agg0,
      waR + WA, waR + WA + 256, waN + WA, waN + WA + 256, 2 * C_, aB + 256, curB, nullptr); // curr2
  agg2_k<<<AGG_GRID, 256, 0, stream>>>(latA, curB, row_ptr, colx, agg1, agg0);  // agg(lat3), agg(curr2)
  // base layer 3 -> d_out first half (f32) + bf16 copy for agg(lat4)
  gemm_k<2><<<GEMM_GRID, 256, 0, stream>>>(latA, agg1, nullptr, nullptr,
      wbR + 3 * WB, wbN + 3 * WB, nullptr, nullptr, C_, bB + 768, latB, out);    // lat4
  // adapter layer 2: concat(lat3, curr2)
  gemm_k<4><<<GEMM_GRID, 256, 0, stream>>>(latA, curB, agg1, agg0,
      waR + 2 * WA, waR + 2 * WA + 256, waN + 2 * WA, waN + 2 * WA + 256, 2 * C_, aB + 512, curA, nullptr); // curr3
  agg2_k<<<AGG_GRID, 256, 0, stream>>>(latB, curA, row_ptr, colx, agg1, agg0);  // agg(lat4), agg(curr3)
  // adapter layer 3 -> d_out second half (f32 only)
  gemm_k<4><<<GEMM_GRID, 256, 0, stream>>>(latB, curA, agg1, agg0,
      waR + 3 * WA, waR + 3 * WA + 256, waN + 3 * WA, waN + 3 * WA + 256, 2 * C_, aB + 768,
      nullptr, out + (size_t)BN_ * C_);
}

// Round 6
// 1102.863 us; speedup vs baseline: 1.1317x; 1.1186x over previous
//
#include <hip/hip_runtime.h>

#define B_ 8
#define N_ 8192
#define C_ 256
#define L_ 4
#define E_ 131072
#define BN_ 65536        // B_*N_
#define EDGES_ 1048576   // B_*E_
#define NKEY_ (BN_ * 4)  // CSR keys: (node, src_tile of 2048)

typedef __attribute__((ext_vector_type(8))) short short8;
typedef __attribute__((ext_vector_type(4))) float f32x4;

__device__ __forceinline__ unsigned short f2bf(float f){
  unsigned int u = __builtin_bit_cast(unsigned int, f);
  u += 0x7fffu + ((u >> 16) & 1u);
  return (unsigned short)(u >> 16);
}
__device__ __forceinline__ float bf2f(unsigned short h){
  unsigned int u = ((unsigned int)h) << 16;
  return __builtin_bit_cast(float, u);
}

// ---------------- f32 -> bf16 convert (x4 vectorized) ----------------
__launch_bounds__(256)
__global__ void cvt_bf16_k(const float* __restrict__ in, unsigned short* __restrict__ out, int n4){
  int t = blockIdx.x * 256 + threadIdx.x;
  if (t >= n4) return;
  float4 v = ((const float4*)in)[t];
  ushort4 o;
  o.x = f2bf(v.x); o.y = f2bf(v.y); o.z = f2bf(v.z); o.w = f2bf(v.w);
  ((ushort4*)out)[t] = o;
}

// -------- CSR build: counting sort by key = (dst, src>>11) --------
// src-tile ordering makes concurrent gather waves touch a 1 MiB window per
// table (L2-resident per XCD) instead of cycling the whole 4 MiB table.
__launch_bounds__(256)
__global__ void hist_k(const int* __restrict__ ei, int* __restrict__ cnt){
  int t = blockIdx.x * 256 + threadIdx.x;
  int b = t >> 17, e = t & (E_ - 1);
  int src = ei[b * (2 * E_) + e];
  int dst = ei[b * (2 * E_) + E_ + e];
  int key = (((b << 13) + dst) << 2) | (src >> 11);
  atomicAdd(&cnt[key], 1);
}

// -------- parallel 3-pass exclusive scan over NKEY_ counters --------
// pass A: 256 blocks x 1024 keys -> per-block sum
__launch_bounds__(256)
__global__ void scanA_k(const int* __restrict__ cnt, int* __restrict__ bsum){
  __shared__ int ls[256];
  int b = blockIdx.x, t = threadIdx.x;
  int4 v = *(const int4*)(cnt + b * 1024 + t * 4);
  int s = v.x + v.y + v.z + v.w;
  ls[t] = s;
  __syncthreads();
  for (int d = 128; d > 0; d >>= 1){
    if (t < d) ls[t] += ls[t + d];
    __syncthreads();
  }
  if (t == 0) bsum[b] = ls[0];
}
// pass B: 1 block scans the 256 block sums -> exclusive block offsets
__launch_bounds__(256)
__global__ void scanB_k(const int* __restrict__ bsum, int* __restrict__ boff){
  __shared__ int ls[256];
  int t = threadIdx.x;
  int v = bsum[t];
  ls[t] = v;
  __syncthreads();
  for (int d = 1; d < 256; d <<= 1){
    int x = (t >= d) ? ls[t - d] : 0;
    __syncthreads();
    ls[t] += x;
    __syncthreads();
  }
  boff[t] = ls[t] - v;
}
// pass C: per-block local scan + block offset -> row_ptr & cursor
__launch_bounds__(256)
__global__ void scanC_k(const int* __restrict__ cnt, const int* __restrict__ boff,
                        int* __restrict__ row_ptr, int* __restrict__ cursor){
  __shared__ int ls[256];
  int b = blockIdx.x, t = threadIdx.x;
  int base = b * 1024 + t * 4;
  int4 v = *(const int4*)(cnt + base);
  int s = v.x + v.y + v.z + v.w;
  ls[t] = s;
  __syncthreads();
  for (int d = 1; d < 256; d <<= 1){
    int x = (t >= d) ? ls[t - d] : 0;
    __syncthreads();
    ls[t] += x;
    __syncthreads();
  }
  int off = boff[b] + ls[t] - s;       // exclusive prefix for key base+0
  int4 rp;
  rp.x = off;
  rp.y = off + v.x;
  rp.z = rp.y + v.y;
  rp.w = rp.z + v.z;
  *(int4*)(row_ptr + base) = rp;
  *(int4*)(cursor + base) = rp;
  if (b == 255 && t == 255) row_ptr[NKEY_] = EDGES_;  // total is fixed: B_*E_
}

__launch_bounds__(256)
__global__ void scat_k(const int* __restrict__ ei, int* __restrict__ cursor, int* __restrict__ col){
  int t = blockIdx.x * 256 + threadIdx.x;
  int b = t >> 17, e = t & (E_ - 1);
  int src = ei[b * (2 * E_) + e];
  int dst = ei[b * (2 * E_) + E_ + e];
  int key = (((b << 13) + dst) << 2) | (src >> 11);
  int pos = atomicAdd(&cursor[key], 1);
  col[pos] = (b << 13) + src;
}

// ---- aggregation: one wave per dst node, CSR (src-tile ordered), f32 accum ----
// blockIdx%8 = graph id -> pins each graph's tables to one XCD's L2.
__launch_bounds__(256)
__global__ void agg_k(const unsigned short* __restrict__ feat, const int* __restrict__ row_ptr,
                      const int* __restrict__ col, unsigned short* __restrict__ out){
  int w = threadIdx.x >> 6, lane = threadIdx.x & 63;
  int g = blockIdx.x & 7, sblk = blockIdx.x >> 3;
  int node = (g << 13) + (sblk << 2) + w;
  int beg = row_ptr[node << 2], end = row_ptr[(node << 2) + 4];
  int ch = lane << 2;  // 4 channels per lane
  float a0=0,a1=0,a2=0,a3=0;
  int e = beg;
  for (; e + 4 <= end; e += 4){
    int s0 = col[e], s1 = col[e+1], s2 = col[e+2], s3 = col[e+3];
    ushort4 v0 = *(const ushort4*)(feat + ((size_t)s0 << 8) + ch);
    ushort4 v1 = *(const ushort4*)(feat + ((size_t)s1 << 8) + ch);
    ushort4 v2 = *(const ushort4*)(feat + ((size_t)s2 << 8) + ch);
    ushort4 v3 = *(const ushort4*)(feat + ((size_t)s3 << 8) + ch);
    a0 += (bf2f(v0.x) + bf2f(v1.x)) + (bf2f(v2.x) + bf2f(v3.x));
    a1 += (bf2f(v0.y) + bf2f(v1.y)) + (bf2f(v2.y) + bf2f(v3.y));
    a2 += (bf2f(v0.z) + bf2f(v1.z)) + (bf2f(v2.z) + bf2f(v3.z));
    a3 += (bf2f(v0.w) + bf2f(v1.w)) + (bf2f(v2.w) + bf2f(v3.w));
  }
  for (; e < end; ++e){
    int s0 = col[e];
    ushort4 v0 = *(const ushort4*)(feat + ((size_t)s0 << 8) + ch);
    a0 += bf2f(v0.x); a1 += bf2f(v0.y); a2 += bf2f(v0.z); a3 += bf2f(v0.w);
  }
  ushort4 o;
  o.x = f2bf(a0); o.y = f2bf(a1); o.z = f2bf(a2); o.w = f2bf(a3);
  *(ushort4*)(out + ((size_t)node << 8) + ch) = o;
}

// ---- fused dual aggregation: same CSR walk, gather two tables at once ----
__launch_bounds__(256)
__global__ void agg2_k(const unsigned short* __restrict__ fA, const unsigned short* __restrict__ fB,
                       const int* __restrict__ row_ptr, const int* __restrict__ col,
                       unsigned short* __restrict__ oA, unsigned short* __restrict__ oB){
  int w = threadIdx.x >> 6, lane = threadIdx.x & 63;
  int g = blockIdx.x & 7, sblk = blockIdx.x >> 3;
  int node = (g << 13) + (sblk << 2) + w;
  int beg = row_ptr[node << 2], end = row_ptr[(node << 2) + 4];
  int ch = lane << 2;
  float a0=0,a1=0,a2=0,a3=0, c0=0,c1=0,c2=0,c3=0;
  int e = beg;
  for (; e + 4 <= end; e += 4){
    int s0 = col[e], s1 = col[e+1], s2 = col[e+2], s3 = col[e+3];
    ushort4 va0 = *(const ushort4*)(fA + ((size_t)s0 << 8) + ch);
    ushort4 va1 = *(const ushort4*)(fA + ((size_t)s1 << 8) + ch);
    ushort4 va2 = *(const ushort4*)(fA + ((size_t)s2 << 8) + ch);
    ushort4 va3 = *(const ushort4*)(fA + ((size_t)s3 << 8) + ch);
    ushort4 vb0 = *(const ushort4*)(fB + ((size_t)s0 << 8) + ch);
    ushort4 vb1 = *(const ushort4*)(fB + ((size_t)s1 << 8) + ch);
    ushort4 vb2 = *(const ushort4*)(fB + ((size_t)s2 << 8) + ch);
    ushort4 vb3 = *(const ushort4*)(fB + ((size_t)s3 << 8) + ch);
    a0 += (bf2f(va0.x) + bf2f(va1.x)) + (bf2f(va2.x) + bf2f(va3.x));
    a1 += (bf2f(va0.y) + bf2f(va1.y)) + (bf2f(va2.y) + bf2f(va3.y));
    a2 += (bf2f(va0.z) + bf2f(va1.z)) + (bf2f(va2.z) + bf2f(va3.z));
    a3 += (bf2f(va0.w) + bf2f(va1.w)) + (bf2f(va2.w) + bf2f(va3.w));
    c0 += (bf2f(vb0.x) + bf2f(vb1.x)) + (bf2f(vb2.x) + bf2f(vb3.x));
    c1 += (bf2f(vb0.y) + bf2f(vb1.y)) + (bf2f(vb2.y) + bf2f(vb3.y));
    c2 += (bf2f(vb0.z) + bf2f(vb1.z)) + (bf2f(vb2.z) + bf2f(vb3.z));
    c3 += (bf2f(vb0.w) + bf2f(vb1.w)) + (bf2f(vb2.w) + bf2f(vb3.w));
  }
  for (; e < end; ++e){
    int s0 = col[e];
    ushort4 va0 = *(const ushort4*)(fA + ((size_t)s0 << 8) + ch);
    ushort4 vb0 = *(const ushort4*)(fB + ((size_t)s0 << 8) + ch);
    a0 += bf2f(va0.x); a1 += bf2f(va0.y); a2 += bf2f(va0.z); a3 += bf2f(va0.w);
    c0 += bf2f(vb0.x); c1 += bf2f(vb0.y); c2 += bf2f(vb0.z); c3 += bf2f(vb0.w);
  }
  ushort4 oa, ob;
  oa.x = f2bf(a0); oa.y = f2bf(a1); oa.z = f2bf(a2); oa.w = f2bf(a3);
  ob.x = f2bf(c0); ob.y = f2bf(c1); ob.z = f2bf(c2); ob.w = f2bf(c3);
  *(ushort4*)(oA + ((size_t)node << 8) + ch) = oa;
  *(ushort4*)(oB + ((size_t)node << 8) + ch) = ob;
}

// ---------------- multi-operand GEMM: out = relu(sum_p A_p @ W_p.T + b) ----------------
// 128x256 tile, 4 waves (wave tile 32x256, acc[2][16]).
// 2-phase pipeline (T3 minimum): double-buffered 24KB LDS, STAGE(next) issued
// before compute(cur), ONE vmcnt(0)+s_barrier per k-step.
#define GLDS16(gp, lp) __builtin_amdgcn_global_load_lds( \
    (const __attribute__((address_space(1))) void*)(gp), \
    (__attribute__((address_space(3))) void*)(lp), 16, 0, 0)

template<int P>
__launch_bounds__(256)
__global__ void gemm_k(const unsigned short* __restrict__ A0, const unsigned short* __restrict__ A1,
                       const unsigned short* __restrict__ A2, const unsigned short* __restrict__ A3,
                       const unsigned short* __restrict__ W0, const unsigned short* __restrict__ W1,
                       const unsigned short* __restrict__ W2, const unsigned short* __restrict__ W3,
                       int ldw, const float* __restrict__ bias,
                       unsigned short* __restrict__ outb, float* __restrict__ outf){
  __shared__ unsigned short lds_u[24576];            // 48 KiB: 2 x (A 8K + B 16K)
  const unsigned short* As[4] = {A0, A1, A2, A3};
  const unsigned short* Ws[4] = {W0, W1, W2, W3};
  const int m0 = blockIdx.x << 7;
  const int t = threadIdx.x, lane = t & 63;
  const int w = t >> 6;                              // wave id: rows w*32..w*32+31
  const int lrow = lane & 15, kg = lane >> 4;
  f32x4 acc[2][16] = {};
  int cur = 0;

#pragma unroll
  for (int p = 0; p < P; ++p){
    const unsigned short* A = As[p] + (size_t)m0 * C_;
    const unsigned short* W = Ws[p];
    // op prologue: stage k-step 0 into buf[cur], full drain
    {
      unsigned short* a_t = lds_u + cur * 12288;
      unsigned short* b_t = a_t + 4096;
#pragma unroll
      for (int c = t; c < 512; c += 256){
        int row = c >> 2, seg = c & 3;
        GLDS16(A + row * C_  + seg * 8, &a_t[c * 8]);
      }
#pragma unroll
      for (int c = t; c < 1024; c += 256){
        int row = c >> 2, seg = c & 3;
        GLDS16(W + row * ldw + seg * 8, &b_t[c * 8]);
      }
      asm volatile("s_waitcnt vmcnt(0)" ::: "memory");
      __builtin_amdgcn_s_barrier();
    }
    for (int ks = 0; ks < 8; ++ks){
      if (ks < 7){                                   // stage NEXT k-step into buf[cur^1]
        int k0 = (ks + 1) << 5;
        unsigned short* a_t = lds_u + (cur ^ 1) * 12288;
        unsigned short* b_t = a_t + 4096;
#pragma unroll
        for (int c = t; c < 512; c += 256){
          int row = c >> 2, seg = c & 3;
          GLDS16(A + row * C_  + k0 + seg * 8, &a_t[c * 8]);
        }
#pragma unroll
        for (int c = t; c < 1024; c += 256){
          int row = c >> 2, seg = c & 3;
          GLDS16(W + row * ldw + k0 + seg * 8, &b_t[c * 8]);
        }
      }
      // compute on buf[cur]
      {
        const unsigned short* a_t = lds_u + cur * 12288;
        const unsigned short* b_t = a_t + 4096;
        short8 af[2];
#pragma unroll
        for (int m = 0; m < 2; ++m)
          af[m] = *(const short8*)&a_t[((w << 5) + (m << 4) + lrow) * 32 + (kg << 3)];
#pragma unroll
        for (int h = 0; h < 2; ++h){
          short8 bfr[8];
#pragma unroll
          for (int n2 = 0; n2 < 8; ++n2)
            bfr[n2] = *(const short8*)&b_t[((h << 7) + (n2 << 4) + lrow) * 32 + (kg << 3)];
#pragma unroll
          for (int m = 0; m < 2; ++m)
#pragma unroll
            for (int n2 = 0; n2 < 8; ++n2)
              acc[m][(h << 3) + n2] =
                  __builtin_amdgcn_mfma_f32_16x16x32_bf16(af[m], bfr[n2], acc[m][(h << 3) + n2], 0, 0, 0);
        }
      }
      // next-tile loads complete + all waves done reading buf[cur]
      asm volatile("s_waitcnt vmcnt(0)" ::: "memory");
      __builtin_amdgcn_s_barrier();
      cur ^= 1;
    }
  }
  // ---- epilogue: bias + relu; both outputs via LDS transpose, coalesced ----
  float bv[16];
#pragma unroll
  for (int n = 0; n < 16; ++n) bv[n] = bias[(n << 4) + lrow];
  unsigned short* ep  = lds_u + (w << 11);           // [16][128] bf16, 4KB
  float*          epf = (float*)(&lds_u[8192]) + (w << 11); // [16][128] f32, 8KB
#pragma unroll
  for (int m = 0; m < 2; ++m){
    const int gr = m0 + (w << 5) + (m << 4);
    if (outf){
#pragma unroll
      for (int h = 0; h < 2; ++h){
#pragma unroll
        for (int n2 = 0; n2 < 8; ++n2){
          int n = (h << 3) + n2;
#pragma unroll
          for (int j = 0; j < 4; ++j){
            float v = acc[m][n][j] + bv[n];
            v = v > 0.f ? v : 0.f;
            epf[((kg << 2) + j) * 128 + (n2 << 4) + lrow] = v;
          }
        }
#pragma unroll
        for (int k = 0; k < 8; ++k){
          int r = (lane >> 5) + (k << 1);
          float4 v = *(const float4*)&epf[r * 128 + (lane & 31) * 4];
          *(float4*)&outf[(size_t)(gr + r) * C_ + (h << 7) + (lane & 31) * 4] = v;
        }
      }
    }
    if (outb){
#pragma unroll
      for (int h = 0; h < 2; ++h){                   // column halves of 256
#pragma unroll
        for (int n2 = 0; n2 < 8; ++n2){
          int n = (h << 3) + n2;
#pragma unroll
          for (int j = 0; j < 4; ++j){
            float v = acc[m][n][j] + bv[n];
            v = v > 0.f ? v : 0.f;
            ep[((kg << 2) + j) * 128 + (n2 << 4) + lrow] = f2bf(v);
          }
        }
#pragma unroll
        for (int k = 0; k < 4; ++k){
          int r = (lane >> 4) + (k << 2);
          short8 v = *(const short8*)&ep[r * 128 + (lane & 15) * 8];
          *(short8*)&outb[(size_t)(gr + r) * C_ + (h << 7) + (lane & 15) * 8] = v;
        }
      }
    }
  }
}

// ---------------------------------------------------------------------------
extern "C" void kernel_launch(void* const* d_in, const int* in_sizes, int n_in,
                              void* d_out, int out_size, void* d_ws, size_t ws_size,
                              hipStream_t stream){
  const float* x_f   = (const float*)d_in[0];
  const float* bWr_f = (const float*)d_in[1];
  const float* bWn_f = (const float*)d_in[2];
  const float* bB    = (const float*)d_in[3];
  const float* aWr_f = (const float*)d_in[4];
  const float* aWn_f = (const float*)d_in[5];
  const float* aB    = (const float*)d_in[6];
  const int*   ei    = (const int*)d_in[7];
  float* out = (float*)d_out;
  (void)in_sizes; (void)n_in; (void)out_size; (void)ws_size;

  char* p = (char*)d_ws;
  const size_t BUF = (size_t)BN_ * C_ * sizeof(unsigned short); // 32 MiB
  auto alloc = [&](size_t bytes){ void* r = (void*)p; p += (bytes + 255) & ~(size_t)255; return r; };
  unsigned short* xb   = (unsigned short*)alloc(BUF);
  unsigned short* latA = (unsigned short*)alloc(BUF);
  unsigned short* latB = (unsigned short*)alloc(BUF);
  unsigned short* curA = (unsigned short*)alloc(BUF);
  unsigned short* curB = (unsigned short*)alloc(BUF);
  unsigned short* agg0 = (unsigned short*)alloc(BUF);
  unsigned short* agg1 = (unsigned short*)alloc(BUF);
  unsigned short* wbR  = (unsigned short*)alloc((size_t)L_ * C_ * C_ * 2);
  unsigned short* wbN  = (unsigned short*)alloc((size_t)L_ * C_ * C_ * 2);
  unsigned short* waR  = (unsigned short*)alloc((size_t)L_ * C_ * 2 * C_ * 2);
  unsigned short* waN  = (unsigned short*)alloc((size_t)L_ * C_ * 2 * C_ * 2);
  int* cnt     = (int*)alloc((size_t)NKEY_ * 4);
  int* row_ptr = (int*)alloc((size_t)(NKEY_ + 1) * 4);
  int* cursor  = (int*)alloc((size_t)NKEY_ * 4);
  int* colx    = (int*)alloc((size_t)EDGES_ * 4);
  int* bsum    = (int*)alloc(256 * 4);
  int* boff    = (int*)alloc(256 * 4);

  // bf16 conversions
  cvt_bf16_k<<<BN_ * C_ / 4 / 256, 256, 0, stream>>>(x_f, xb, BN_ * C_ / 4);
  cvt_bf16_k<<<L_ * C_ * C_ / 4 / 256, 256, 0, stream>>>(bWr_f, wbR, L_ * C_ * C_ / 4);
  cvt_bf16_k<<<L_ * C_ * C_ / 4 / 256, 256, 0, stream>>>(bWn_f, wbN, L_ * C_ * C_ / 4);
  cvt_bf16_k<<<L_ * C_ * 2 * C_ / 4 / 256, 256, 0, stream>>>(aWr_f, waR, L_ * C_ * 2 * C_ / 4);
  cvt_bf16_k<<<L_ * C_ * 2 * C_ / 4 / 256, 256, 0, stream>>>(aWn_f, waN, L_ * C_ * 2 * C_ / 4);

  // CSR build (src-tiled counting sort, parallel 3-pass scan)
  hipMemsetAsync(cnt, 0, (size_t)NKEY_ * 4, stream);
  hist_k<<<EDGES_ / 256, 256, 0, stream>>>(ei, cnt);
  scanA_k<<<256, 256, 0, stream>>>(cnt, bsum);
  scanB_k<<<1, 256, 0, stream>>>(bsum, boff);
  scanC_k<<<256, 256, 0, stream>>>(cnt, boff, row_ptr, cursor);
  scat_k<<<EDGES_ / 256, 256, 0, stream>>>(ei, cursor, colx);

  const int AGG_GRID  = BN_ / 4;     // 16384 blocks, 4 waves/block, 1 node/wave
  const int GEMM_GRID = BN_ / 128;   // 512 blocks, full N per block

  const size_t WB = (size_t)C_ * C_;       // base per-layer weight elems
  const size_t WA = (size_t)C_ * 2 * C_;   // adapter per-layer weight elems

  // base layer 0: lat1 = relu(x@Wr0.T + agg(x)@Wn0.T + b0)
  agg_k<<<AGG_GRID, 256, 0, stream>>>(xb, row_ptr, colx, agg0);                 // agg(x)
  gemm_k<2><<<GEMM_GRID, 256, 0, stream>>>(xb, agg0, nullptr, nullptr,
      wbR, wbN, nullptr, nullptr, C_, bB, latA, nullptr);                        // lat1
  agg_k<<<AGG_GRID, 256, 0, stream>>>(latA, row_ptr, colx, agg1);               // agg(lat1)
  // base layer 1
  gemm_k<2><<<GEMM_GRID, 256, 0, stream>>>(latA, agg1, nullptr, nullptr,
      wbR + WB, wbN + WB, nullptr, nullptr, C_, bB + 256, latB, nullptr);        // lat2
  // adapter layer 0: concat(lat1, x)
  gemm_k<4><<<GEMM_GRID, 256, 0, stream>>>(latA, xb, agg1, agg0,
      waR, waR + 256, waN, waN + 256, 2 * C_, aB, curA, nullptr);                // curr1
  agg2_k<<<AGG_GRID, 256, 0, stream>>>(latB, curA, row_ptr, colx, agg1, agg0);  // agg(lat2), agg(curr1)
  // base layer 2
  gemm_k<2><<<GEMM_GRID, 256, 0, stream>>>(latB, agg1, nullptr, nullptr,
      wbR + 2 * WB, wbN + 2 * WB, nullptr, nullptr, C_, bB + 512, latA, nullptr); // lat3
  // adapter layer 1: concat(lat2, curr1)
  gemm_k<4><<<GEMM_GRID, 256, 0, stream>>>(latB, curA, agg1, agg0,
      waR + WA, waR + WA + 256, waN + WA, waN + WA + 256, 2 * C_, aB + 256, curB, nullptr); // curr2
  agg2_k<<<AGG_GRID, 256, 0, stream>>>(latA, curB, row_ptr, colx, agg1, agg0);  // agg(lat3), agg(curr2)
  // base layer 3 -> d_out first half (f32) + bf16 copy for agg(lat4)
  gemm_k<2><<<GEMM_GRID, 256, 0, stream>>>(latA, agg1, nullptr, nullptr,
      wbR + 3 * WB, wbN + 3 * WB, nullptr, nullptr, C_, bB + 768, latB, out);    // lat4
  // adapter layer 2: concat(lat3, curr2)
  gemm_k<4><<<GEMM_GRID, 256, 0, stream>>>(latA, curB, agg1, agg0,
      waR + 2 * WA, waR + 2 * WA + 256, waN + 2 * WA, waN + 2 * WA + 256, 2 * C_, aB + 512, curA, nullptr); // curr3
  agg2_k<<<AGG_GRID, 256, 0, stream>>>(latB, curA, row_ptr, colx, agg1, agg0);  // agg(lat4), agg(curr3)
  // adapter layer 3 -> d_out second half (f32 only)
  gemm_k<4><<<GEMM_GRID, 256, 0, stream>>>(latB, curA, agg1, agg0,
      waR + 3 * WA, waR + 3 * WA + 256, waN + 3 * WA, waN + 3 * WA + 256, 2 * C_, aB + 768,
      nullptr, out + (size_t)BN_ * C_);
}